// Round 1
// baseline (1077.419 us; speedup 1.0000x reference)
//
#include <hip/hip_runtime.h>
#include <stdint.h>

#define ECH 64
#define HID 128
#define OCH 128
#define WPB 8
#define BLK 512
#define EB 4

// LDS float layout: W1[64*128]=8192 | W2[128*128]=16384 | b1[128] b2[128] attn[128]
// then per-wave scratch: ean[EB*64] + h[EB*128] = 768 floats
#define SM_W2   8192
#define SM_B1   24576
#define SM_B2   24704
#define SM_ATT  24832
#define SM_WV   24960
#define SM_TOTF (SM_WV + WPB*768)

__device__ __forceinline__ unsigned enc_f(float f){
  unsigned u = __float_as_uint(f);
  return (u & 0x80000000u) ? ~u : (u | 0x80000000u);
}
__device__ __forceinline__ float dec_f(unsigned u){
  return (u & 0x80000000u) ? __uint_as_float(u & 0x7fffffffu) : __uint_as_float(~u);
}
__device__ __forceinline__ float tanh_fast(float x){
  float e = __expf(2.0f * x);
  return 1.0f - 2.0f / (e + 1.0f);   // saturates correctly at +-1 for large |x|
}
__device__ __forceinline__ unsigned pack_bf16x2(float x, float y){
  unsigned ux = __float_as_uint(x), uy = __float_as_uint(y);
  unsigned rx = (ux + 0x7fffu + ((ux >> 16) & 1u)) >> 16;
  unsigned ry = (uy + 0x7fffu + ((uy >> 16) & 1u)) & 0xffff0000u;
  return (rx & 0xffffu) | ry;
}
__device__ __forceinline__ float2 unpack_bf16x2(unsigned p){
  float2 r;
  r.x = __uint_as_float(p << 16);
  r.y = __uint_as_float(p & 0xffff0000u);
  return r;
}

// MODE 0: compute score + store bf16 messages (path A pass 1)
// MODE 1: compute score only                  (path B pass 1)
// MODE 2: recompute messages, apply softmax weights, scatter (path B pass 3)
template<int MODE>
__launch_bounds__(BLK, 1)
__global__ void cfconv_mlp(const float* __restrict__ x,
                           const int* __restrict__ ei,
                           const float* __restrict__ ea,
                           const float* __restrict__ W1,
                           const float* __restrict__ b1,
                           const float* __restrict__ W2,
                           const float* __restrict__ b2,
                           const float* __restrict__ attn,
                           float* __restrict__ scorep,
                           unsigned* __restrict__ segmax,
                           const float* __restrict__ denom,
                           unsigned* __restrict__ msgp,
                           float* __restrict__ out,
                           int N, int E)
{
  extern __shared__ float smem[];
  // ---- stage weights ----
  for (int i = threadIdx.x * 4; i < 8192; i += BLK * 4)
    *(float4*)&smem[i] = *(const float4*)&W1[i];
  for (int i = threadIdx.x * 4; i < 16384; i += BLK * 4)
    *(float4*)&smem[SM_W2 + i] = *(const float4*)&W2[i];
  if (threadIdx.x < 128) {
    smem[SM_B1  + threadIdx.x] = b1[threadIdx.x];
    smem[SM_B2  + threadIdx.x] = b2[threadIdx.x];
    smem[SM_ATT + threadIdx.x] = attn[threadIdx.x];
  }
  __syncthreads();

  const int lane = threadIdx.x & 63;
  const int wid  = threadIdx.x >> 6;
  float* sE = smem + SM_WV + wid * 768;      // ean [EB][64]
  float* sH = sE + EB * ECH;                 // h   [EB][128]
  const float2 b1v = *(const float2*)&smem[SM_B1  + 2 * lane];
  const float2 b2v = *(const float2*)&smem[SM_B2  + 2 * lane];
  const float2 atv = *(const float2*)&smem[SM_ATT + 2 * lane];
  const float* w1l = smem + 2 * lane;
  const float* w2l = smem + SM_W2 + 2 * lane;

  const long long totalWaves = (long long)gridDim.x * WPB;
  for (long long base = ((long long)blockIdx.x * WPB + wid) * EB;
       base < E; base += totalWaves * EB) {
    const int nb = (int)min((long long)EB, (long long)E - base);

    float a[EB]; int srcb[EB], tgtb[EB]; float2 xv[EB];
#pragma unroll
    for (int b = 0; b < EB; ++b) {
      long long e = base + (b < nb ? b : 0);
      a[b]    = ea[e * ECH + lane];
      srcb[b] = ei[e];
      tgtb[b] = ei[(long long)E + e];
    }
#pragma unroll
    for (int b = 0; b < EB; ++b)
      xv[b] = *(const float2*)&x[(long long)srcb[b] * 128 + 2 * lane];

    // ---- norm ----
    float ss[EB];
#pragma unroll
    for (int b = 0; b < EB; ++b) ss[b] = a[b] * a[b];
#pragma unroll
    for (int off = 32; off; off >>= 1) {
#pragma unroll
      for (int b = 0; b < EB; ++b) ss[b] += __shfl_xor(ss[b], off);
    }
#pragma unroll
    for (int b = 0; b < EB; ++b) {
      float rin = 1.0f / (sqrtf(ss[b]) + 1e-8f);
      sE[b * ECH + lane] = a[b] * rin;
    }
    asm volatile("s_waitcnt lgkmcnt(0)" ::: "memory");

    // ---- h = tanh(ean @ W1 + b1) ----
    float2 hacc[EB];
#pragma unroll
    for (int b = 0; b < EB; ++b) hacc[b] = make_float2(0.f, 0.f);
#pragma unroll 4
    for (int k4 = 0; k4 < 16; ++k4) {
      float4 ebv[EB];
#pragma unroll
      for (int b = 0; b < EB; ++b) ebv[b] = *(const float4*)&sE[b * ECH + k4 * 4];
#pragma unroll
      for (int kk = 0; kk < 4; ++kk) {
        float2 w = *(const float2*)&w1l[(k4 * 4 + kk) * HID];
#pragma unroll
        for (int b = 0; b < EB; ++b) {
          float ev = ((const float*)&ebv[b])[kk];
          hacc[b].x = fmaf(ev, w.x, hacc[b].x);
          hacc[b].y = fmaf(ev, w.y, hacc[b].y);
        }
      }
    }
#pragma unroll
    for (int b = 0; b < EB; ++b) {
      float2 t;
      t.x = tanh_fast(hacc[b].x + b1v.x);
      t.y = tanh_fast(hacc[b].y + b1v.y);
      *(float2*)&sH[b * HID + 2 * lane] = t;
    }
    asm volatile("s_waitcnt lgkmcnt(0)" ::: "memory");

    // ---- f = h @ W2 + b2 ----
    float2 facc[EB];
#pragma unroll
    for (int b = 0; b < EB; ++b) facc[b] = make_float2(0.f, 0.f);
#pragma unroll 4
    for (int j4 = 0; j4 < 32; ++j4) {
      float4 hbv[EB];
#pragma unroll
      for (int b = 0; b < EB; ++b) hbv[b] = *(const float4*)&sH[b * HID + j4 * 4];
#pragma unroll
      for (int kk = 0; kk < 4; ++kk) {
        float2 w = *(const float2*)&w2l[(j4 * 4 + kk) * HID];
#pragma unroll
        for (int b = 0; b < EB; ++b) {
          float hv = ((const float*)&hbv[b])[kk];
          facc[b].x = fmaf(hv, w.x, facc[b].x);
          facc[b].y = fmaf(hv, w.y, facc[b].y);
        }
      }
    }

    // ---- messages + scores ----
    float2 msg[EB]; float p[EB];
#pragma unroll
    for (int b = 0; b < EB; ++b) {
      float2 f;
      f.x = facc[b].x + b2v.x;
      f.y = facc[b].y + b2v.y;
      msg[b].x = xv[b].x * f.x;
      msg[b].y = xv[b].y * f.y;
      p[b] = msg[b].x * atv.x + msg[b].y * atv.y;
    }
#pragma unroll
    for (int off = 32; off; off >>= 1) {
#pragma unroll
      for (int b = 0; b < EB; ++b) p[b] += __shfl_xor(p[b], off);
    }

    if (MODE == 0) {
#pragma unroll
      for (int b = 0; b < EB; ++b)
        if (b < nb)
          msgp[(base + b) * 64 + lane] = pack_bf16x2(msg[b].x, msg[b].y);
    }
    if (MODE <= 1) {
      if (lane < nb) {
        float sc = lane == 0 ? p[0] : lane == 1 ? p[1] : lane == 2 ? p[2] : p[3];
        int   tg = lane == 0 ? tgtb[0] : lane == 1 ? tgtb[1] : lane == 2 ? tgtb[2] : tgtb[3];
        scorep[base + lane] = sc;
        atomicMax(&segmax[tg], enc_f(sc));
      }
    }
    if (MODE == 2) {
      float wgt[EB];
#pragma unroll
      for (int b = 0; b < EB; ++b) {
        float sc = scorep[base + b];
        float m  = dec_f(segmax[tgtb[b]]);
        float dn = denom[tgtb[b]];
        wgt[b] = __expf(sc - m) / (dn + 1e-16f);
      }
#pragma unroll
      for (int b = 0; b < EB; ++b) {
        if (b < nb) {
          atomicAdd(&out[(long long)tgtb[b] * 128 + 2 * lane],     msg[b].x * wgt[b]);
          atomicAdd(&out[(long long)tgtb[b] * 128 + 2 * lane + 1], msg[b].y * wgt[b]);
        }
      }
      if (lane < nb) {
        float w = lane == 0 ? wgt[0] : lane == 1 ? wgt[1] : lane == 2 ? wgt[2] : wgt[3];
        out[(long long)N * 128 + base + lane] = w;
      }
    }
  }
}

__global__ void cfconv_pass2(const float* __restrict__ scorep,
                             const unsigned* __restrict__ segmax,
                             const int* __restrict__ ei,
                             float* __restrict__ denom, int N, int E)
{
  for (long long e = (long long)blockIdx.x * blockDim.x + threadIdx.x; e < E;
       e += (long long)gridDim.x * blockDim.x) {
    int tg = ei[(long long)E + e];
    float ex = __expf(scorep[e] - dec_f(segmax[tg]));
    atomicAdd(&denom[tg], ex);
  }
}

__launch_bounds__(256)
__global__ void cfconv_scatter(const unsigned* __restrict__ msgp,
                               const float* __restrict__ scorep,
                               const unsigned* __restrict__ segmax,
                               const float* __restrict__ denom,
                               const int* __restrict__ ei,
                               float* __restrict__ out, int N, int E)
{
  const int lane = threadIdx.x & 63;
  long long gw = (long long)blockIdx.x * (blockDim.x >> 6) + (threadIdx.x >> 6);
  long long tw = (long long)gridDim.x * (blockDim.x >> 6);
  for (long long e = gw; e < E; e += tw) {
    int tg = ei[(long long)E + e];
    float w = __expf(scorep[e] - dec_f(segmax[tg])) / (denom[tg] + 1e-16f);
    float2 mm = unpack_bf16x2(msgp[e * 64 + lane]);
    atomicAdd(&out[(long long)tg * 128 + 2 * lane],     w * mm.x);
    atomicAdd(&out[(long long)tg * 128 + 2 * lane + 1], w * mm.y);
    if (lane == 0) out[(long long)N * 128 + e] = w;
  }
}

extern "C" void kernel_launch(void* const* d_in, const int* in_sizes, int n_in,
                              void* d_out, int out_size, void* d_ws, size_t ws_size,
                              hipStream_t stream)
{
  const float* x    = (const float*)d_in[0];
  const int*   ei   = (const int*)d_in[1];
  const float* ea   = (const float*)d_in[2];
  const float* W1   = (const float*)d_in[3];
  const float* b1   = (const float*)d_in[4];
  const float* W2   = (const float*)d_in[5];
  const float* b2   = (const float*)d_in[6];
  const float* attn = (const float*)d_in[7];
  const int N = in_sizes[0] / 128;
  const int E = in_sizes[2] / 64;
  float* out = (float*)d_out;
  if (E <= 0 || N <= 0) return;

  auto al = [](size_t v){ return (v + 255) & ~(size_t)255; };
  size_t offScore = 0;
  size_t offSeg   = al((size_t)E * 4);
  size_t offDen   = offSeg + al((size_t)N * 4);
  size_t offMsg   = offDen + al((size_t)N * 4);
  size_t needA    = offMsg + (size_t)E * 128 * 2;

  char* wsb = (char*)d_ws;
  float*    scorep = (float*)(wsb + offScore);
  unsigned* segmax = (unsigned*)(wsb + offSeg);
  float*    denom  = (float*)(wsb + offDen);
  unsigned* msgp   = (unsigned*)(wsb + offMsg);
  const bool pathA = ws_size >= needA;

  const size_t lds = (size_t)SM_TOTF * 4;
  hipFuncSetAttribute(reinterpret_cast<const void*>(&cfconv_mlp<0>),
                      hipFuncAttributeMaxDynamicSharedMemorySize, (int)lds);
  hipFuncSetAttribute(reinterpret_cast<const void*>(&cfconv_mlp<1>),
                      hipFuncAttributeMaxDynamicSharedMemorySize, (int)lds);
  hipFuncSetAttribute(reinterpret_cast<const void*>(&cfconv_mlp<2>),
                      hipFuncAttributeMaxDynamicSharedMemorySize, (int)lds);

  hipMemsetAsync(out, 0, (size_t)N * 128 * 4, stream);
  hipMemsetAsync(wsb + offSeg, 0, al((size_t)N * 4) + (size_t)N * 4, stream);

  if (pathA) {
    cfconv_mlp<0><<<256, BLK, lds, stream>>>(x, ei, ea, W1, b1, W2, b2, attn,
                                             scorep, segmax, denom, msgp, out, N, E);
    cfconv_pass2<<<1024, 256, 0, stream>>>(scorep, segmax, ei, denom, N, E);
    cfconv_scatter<<<2048, 256, 0, stream>>>(msgp, scorep, segmax, denom, ei, out, N, E);
  } else {
    cfconv_mlp<1><<<256, BLK, lds, stream>>>(x, ei, ea, W1, b1, W2, b2, attn,
                                             scorep, segmax, denom, msgp, out, N, E);
    cfconv_pass2<<<1024, 256, 0, stream>>>(scorep, segmax, ei, denom, N, E);
    cfconv_mlp<2><<<256, BLK, lds, stream>>>(x, ei, ea, W1, b1, W2, b2, attn,
                                             scorep, segmax, denom, msgp, out, N, E);
  }
}

// Round 2
// 349.959 us; speedup vs baseline: 3.0787x; 3.0787x over previous
//
#include <hip/hip_runtime.h>
#include <stdint.h>

typedef short short8 __attribute__((ext_vector_type(8)));
typedef float f32x16 __attribute__((ext_vector_type(16)));

__device__ __forceinline__ unsigned cvtpk(float lo, float hi){
  unsigned r;
  asm("v_cvt_pk_bf16_f32 %0, %1, %2" : "=v"(r) : "v"(lo), "v"(hi));
  return r;
}

__device__ __forceinline__ short8 frag_from(unsigned a, unsigned b, unsigned c, unsigned d){
  union { unsigned u[4]; short8 s; } t;
  t.u[0] = a; t.u[1] = b; t.u[2] = c; t.u[3] = d;
  return t.s;
}

// ---------------- prep: pack W1^T / W2^T into MFMA A-fragment order ----------------
// frag f<16:  L1, mf=f>>2, ks=f&3 : lane holds W1[kb+j][32*mf + (l&31)], kb=ks*16+(l>>5)*8
// frag f>=16: L2, mf2,ks : lane holds W2[cb+j][32*mf2 + (l&31)], cb=ks*16+(l>>5)*8
__global__ void k_prep(const float* __restrict__ W1, const float* __restrict__ W2,
                       uint4* __restrict__ Wf)
{
  const int t = blockIdx.x * 256 + threadIdx.x;
  if (t >= 48 * 64) return;
  const int f = t >> 6, l = t & 63;
  const int r = l & 31, hh = l >> 5;
  float v[8];
  if (f < 16) {
    const int mf = f >> 2, ks = f & 3;
    const int c = 32 * mf + r, kb = ks * 16 + hh * 8;
#pragma unroll
    for (int j = 0; j < 8; ++j) v[j] = W1[(kb + j) * 128 + c];
  } else {
    const int f2 = f - 16, mf2 = f2 >> 3, ks = f2 & 7;
    const int o = 32 * mf2 + r, cb = ks * 16 + hh * 8;
#pragma unroll
    for (int j = 0; j < 8; ++j) v[j] = W2[(cb + j) * 128 + o];
  }
  uint4 d;
  d.x = cvtpk(v[0], v[1]); d.y = cvtpk(v[2], v[3]);
  d.z = cvtpk(v[4], v[5]); d.w = cvtpk(v[6], v[7]);
  Wf[(long long)f * 64 + l] = d;
}

// ---------------- K1: fused normalize + MLP (MFMA) + messages + scores ----------------
__global__ __launch_bounds__(256)
void k1_fused(const float* __restrict__ x, const int* __restrict__ ei,
              const float* __restrict__ ea, const uint4* __restrict__ Wf,
              const float* __restrict__ b1, const float* __restrict__ b2,
              const float* __restrict__ attn,
              unsigned* __restrict__ msgp, float* __restrict__ scoreb,
              int N, int E)
{
  const int lane = threadIdx.x & 63;
  const int wv   = threadIdx.x >> 6;
  const int h    = lane >> 5;      // which k-half of the fragment this lane holds
  const int r31  = lane & 31;      // edge within the wave's 32-edge group
  const long long e   = (long long)blockIdx.x * 128 + wv * 32 + r31;
  const long long eld = (e < E) ? e : (long long)(E - 1);

  // ---- load edge_attr (this lane: its edge, its 4x8-float k-chunks) + normalize ----
  float av[32];
  const float* earow = ea + eld * 64 + h * 8;
#pragma unroll
  for (int ks = 0; ks < 4; ++ks) {
    float4 p0 = *(const float4*)(earow + ks * 16);
    float4 p1 = *(const float4*)(earow + ks * 16 + 4);
    av[ks*8+0] = p0.x; av[ks*8+1] = p0.y; av[ks*8+2] = p0.z; av[ks*8+3] = p0.w;
    av[ks*8+4] = p1.x; av[ks*8+5] = p1.y; av[ks*8+6] = p1.z; av[ks*8+7] = p1.w;
  }
  const int src = ei[eld];                     // source node (hoisted early)
  float ss = 0.f;
#pragma unroll
  for (int i = 0; i < 32; ++i) ss = fmaf(av[i], av[i], ss);
  ss += __shfl_xor(ss, 32);                    // combine the two k-halves of this edge
  const float rin = 1.0f / (sqrtf(ss) + 1e-8f);

  // ean B-fragments (k = edge channel, col = edge): 4 ksteps x 4 dwords
  unsigned eb[4][4];
#pragma unroll
  for (int ks = 0; ks < 4; ++ks)
#pragma unroll
    for (int d = 0; d < 4; ++d)
      eb[ks][d] = cvtpk(av[ks*8+2*d] * rin, av[ks*8+2*d+1] * rin);

  // ---- L1: D1[c][r] = sum_k W1T[c][k] * ean[r][k] ----
  f32x16 acc1[4];
#pragma unroll
  for (int mf = 0; mf < 4; ++mf)
#pragma unroll
    for (int i = 0; i < 16; ++i) acc1[mf][i] = 0.f;
#pragma unroll
  for (int mf = 0; mf < 4; ++mf)
#pragma unroll
    for (int ks = 0; ks < 4; ++ks) {
      uint4 w = Wf[(mf * 4 + ks) * 64 + lane];
      acc1[mf] = __builtin_amdgcn_mfma_f32_32x32x16_bf16(
          frag_from(w.x, w.y, w.z, w.w), frag_from(eb[ks][0], eb[ks][1], eb[ks][2], eb[ks][3]),
          acc1[mf], 0, 0, 0);
    }

  // ---- bias + tanh, then assemble h B-fragments in-register (half-swap) ----
  // lane's h channels: c = 32*mf + (reg&3) + 8*(reg>>2) + 4*h
  unsigned hb[8][4];
#pragma unroll
  for (int mf = 0; mf < 4; ++mf) {
    float hv[16];
#pragma unroll
    for (int rq = 0; rq < 4; ++rq) {
      float4 bc = *(const float4*)(b1 + 32*mf + 8*rq + 4*h);
#pragma unroll
      for (int i = 0; i < 4; ++i) {
        float pre = acc1[mf][rq*4+i] + ((const float*)&bc)[i];
        float e2  = __expf(2.0f * pre);
        hv[rq*4+i] = 1.0f - 2.0f / (e2 + 1.0f);
      }
    }
#pragma unroll
    for (int q = 0; q < 2; ++q) {             // kstep = 2*mf + q
      unsigned A = cvtpk(hv[q*8+0], hv[q*8+1]);
      unsigned B = cvtpk(hv[q*8+2], hv[q*8+3]);
      unsigned C = cvtpk(hv[q*8+4], hv[q*8+5]);
      unsigned D = cvtpk(hv[q*8+6], hv[q*8+7]);
      unsigned Axr = (unsigned)__shfl_xor((int)A, 32);
      unsigned Bxr = (unsigned)__shfl_xor((int)B, 32);
      unsigned Cxr = (unsigned)__shfl_xor((int)C, 32);
      unsigned Dxr = (unsigned)__shfl_xor((int)D, 32);
      hb[2*mf+q][0] = h ? Cxr : A;
      hb[2*mf+q][1] = h ? Dxr : B;
      hb[2*mf+q][2] = h ? C   : Axr;
      hb[2*mf+q][3] = h ? D   : Bxr;
    }
  }

  // ---- L2: D2[o][r] = sum_c W2T[o][c] * h[r][c] ----
  f32x16 acc2[4];
#pragma unroll
  for (int mf2 = 0; mf2 < 4; ++mf2)
#pragma unroll
    for (int i = 0; i < 16; ++i) acc2[mf2][i] = 0.f;
#pragma unroll
  for (int mf2 = 0; mf2 < 4; ++mf2)
#pragma unroll
    for (int ks = 0; ks < 8; ++ks) {
      uint4 w = Wf[(16 + mf2 * 8 + ks) * 64 + lane];
      acc2[mf2] = __builtin_amdgcn_mfma_f32_32x32x16_bf16(
          frag_from(w.x, w.y, w.z, w.w), frag_from(hb[ks][0], hb[ks][1], hb[ks][2], hb[ks][3]),
          acc2[mf2], 0, 0, 0);
    }

  // ---- epilogue: +b2, * x[src], score, store bf16 messages + f32 score ----
  const float* xrow = x + (long long)src * 128;
  float score = 0.f;
#pragma unroll
  for (int mf2 = 0; mf2 < 4; ++mf2) {
#pragma unroll
    for (int rq = 0; rq < 4; ++rq) {
      const int o0 = 32*mf2 + 8*rq + 4*h;
      float4 b2c = *(const float4*)(b2 + o0);
      float4 xc  = *(const float4*)(xrow + o0);
      float4 atc = *(const float4*)(attn + o0);
      float m0 = (acc2[mf2][rq*4+0] + b2c.x) * xc.x;
      float m1 = (acc2[mf2][rq*4+1] + b2c.y) * xc.y;
      float m2 = (acc2[mf2][rq*4+2] + b2c.z) * xc.z;
      float m3 = (acc2[mf2][rq*4+3] + b2c.w) * xc.w;
      score = fmaf(m0, atc.x, score);
      score = fmaf(m1, atc.y, score);
      score = fmaf(m2, atc.z, score);
      score = fmaf(m3, atc.w, score);
      if (e < E) {
        uint2 st; st.x = cvtpk(m0, m1); st.y = cvtpk(m2, m3);
        *(uint2*)(msgp + e * 64 + 16*mf2 + 4*rq + 2*h) = st;
      }
    }
  }
  score += __shfl_xor(score, 32);
  if (h == 0 && e < E) scoreb[e] = score;
}

// ---------------- CSR build ----------------
__global__ void k_hist(const int* __restrict__ ei, int* __restrict__ cnt, int E){
  for (long long i = (long long)blockIdx.x * 256 + threadIdx.x; i < E;
       i += (long long)gridDim.x * 256)
    atomicAdd(&cnt[ei[E + i]], 1);
}

__global__ __launch_bounds__(1024)
void k_scan(const int* __restrict__ cnt, int* __restrict__ cursor, int N){
  __shared__ int ls[1024];
  const int t = threadIdx.x;
  const int chunk = (N + 1023) >> 10;
  const int c0 = t * chunk, c1 = min(N, c0 + chunk);
  int s = 0;
  for (int i = c0; i < c1; ++i) s += cnt[i];
  ls[t] = s;
  __syncthreads();
  for (int off = 1; off < 1024; off <<= 1) {
    int add = (t >= off) ? ls[t - off] : 0;
    __syncthreads();
    ls[t] += add;
    __syncthreads();
  }
  int run = (t == 0) ? 0 : ls[t - 1];
  for (int i = c0; i < c1; ++i) { cursor[i] = run; run += cnt[i]; }
}

__global__ void k_fill(const int* __restrict__ ei, int* __restrict__ cursor,
                       int* __restrict__ eidx, int E){
  for (long long i = (long long)blockIdx.x * 256 + threadIdx.x; i < E;
       i += (long long)gridDim.x * 256) {
    int tg = ei[E + i];
    int pos = atomicAdd(&cursor[tg], 1);
    eidx[pos] = (int)i;
  }
}

// ---------------- gather: per-node softmax + weighted sum (no atomics) ----------------
__global__ __launch_bounds__(256)
void k_gather(const unsigned* __restrict__ msgp, float* __restrict__ scoreb,
              const int* __restrict__ eidx, const int* __restrict__ cnt,
              const int* __restrict__ cursor, float* __restrict__ out, int N)
{
  const int lane = threadIdx.x & 63;
  const int node = blockIdx.x * 4 + (threadIdx.x >> 6);
  if (node >= N) return;
  const int end = cursor[node];      // after fill, cursor[n] == rowptr[n+1]
  const int L   = cnt[node];
  const int start = end - L;

  float m = -3.4e38f, s = 0.f;
  for (int c0 = 0; c0 < L; c0 += 64) {
    const int j = c0 + lane;
    float sc = -3.4e38f;
    if (j < L) sc = scoreb[eidx[start + j]];
    float cm = sc;
#pragma unroll
    for (int off = 32; off; off >>= 1) cm = fmaxf(cm, __shfl_xor(cm, off));
    const float mn = fmaxf(m, cm);
    float ex = (j < L) ? __expf(sc - mn) : 0.f;
#pragma unroll
    for (int off = 32; off; off >>= 1) ex += __shfl_xor(ex, off);
    s = s * __expf(m - mn) + ex;
    m = mn;
  }
  const float inv = 1.0f / (s + 1e-16f);

  float2 acc; acc.x = 0.f; acc.y = 0.f;
  for (int j = 0; j < L; ++j) {
    const int e2 = eidx[start + j];
    const float w = __expf(scoreb[e2] - m) * inv;
    const unsigned md = msgp[(long long)e2 * 64 + lane];
    float2 mm;
    mm.x = __uint_as_float(md << 16);
    mm.y = __uint_as_float(md & 0xffff0000u);
    acc.x = fmaf(w, mm.x, acc.x);
    acc.y = fmaf(w, mm.y, acc.y);
    if (lane == 0) scoreb[e2] = w;   // final attention weight (each edge visited once)
  }
  *(float2*)(out + (long long)node * 128 + lane * 2) = acc;
}

extern "C" void kernel_launch(void* const* d_in, const int* in_sizes, int n_in,
                              void* d_out, int out_size, void* d_ws, size_t ws_size,
                              hipStream_t stream)
{
  const float* x    = (const float*)d_in[0];
  const int*   ei   = (const int*)d_in[1];
  const float* ea   = (const float*)d_in[2];
  const float* W1   = (const float*)d_in[3];
  const float* b1   = (const float*)d_in[4];
  const float* W2   = (const float*)d_in[5];
  const float* b2   = (const float*)d_in[6];
  const float* attn = (const float*)d_in[7];
  const int N = in_sizes[0] / 128;
  const int E = in_sizes[2] / 64;
  if (E <= 0 || N <= 0) return;

  float* out    = (float*)d_out;
  float* scoreb = out + (long long)N * 128;   // weights region: scores, then final weights
  uint4* Wf     = (uint4*)d_out;              // node-output region: W frags (overwritten by gather)

  char* wsb = (char*)d_ws;
  unsigned* msgp  = (unsigned*)wsb;                       // E * 256 B
  int* eidx       = (int*)(wsb + (size_t)E * 256);        // E * 4
  int* cnt        = eidx + E;                             // N * 4
  int* cursor     = cnt + N;                              // N * 4
  const size_t need = (size_t)E * 256 + (size_t)E * 4 + (size_t)N * 8;
  if (ws_size < need) return;

  hipMemsetAsync(cnt, 0, (size_t)N * 4, stream);
  k_prep<<<12, 256, 0, stream>>>(W1, W2, Wf);
  k_hist<<<2048, 256, 0, stream>>>(ei, cnt, E);
  k1_fused<<<(E + 127) / 128, 256, 0, stream>>>(x, ei, ea, Wf, b1, b2, attn,
                                                msgp, scoreb, N, E);
  k_scan<<<1, 1024, 0, stream>>>(cnt, cursor, N);
  k_fill<<<2048, 256, 0, stream>>>(ei, cursor, eidx, E);
  k_gather<<<(N + 3) / 4, 256, 0, stream>>>(msgp, scoreb, eidx, cnt, cursor, out, N);
}

// Round 3
// 281.682 us; speedup vs baseline: 3.8249x; 1.2424x over previous
//
#include <hip/hip_runtime.h>
#include <stdint.h>

typedef short short8 __attribute__((ext_vector_type(8)));
typedef float f32x16 __attribute__((ext_vector_type(16)));

__device__ __forceinline__ unsigned cvtpk(float lo, float hi){
  unsigned r;
  asm("v_cvt_pk_bf16_f32 %0, %1, %2" : "=v"(r) : "v"(lo), "v"(hi));
  return r;
}

__device__ __forceinline__ short8 frag_from(unsigned a, unsigned b, unsigned c, unsigned d){
  union { unsigned u[4]; short8 s; } t;
  t.u[0] = a; t.u[1] = b; t.u[2] = c; t.u[3] = d;
  return t.s;
}

// ---------------- prep: pack W1^T / W2^T into MFMA A-fragment order ----------------
__global__ void k_prep(const float* __restrict__ W1, const float* __restrict__ W2,
                       uint4* __restrict__ Wf)
{
  const int t = blockIdx.x * 256 + threadIdx.x;
  if (t >= 48 * 64) return;
  const int f = t >> 6, l = t & 63;
  const int r = l & 31, hh = l >> 5;
  float v[8];
  if (f < 16) {
    const int mf = f >> 2, ks = f & 3;
    const int c = 32 * mf + r, kb = ks * 16 + hh * 8;
#pragma unroll
    for (int j = 0; j < 8; ++j) v[j] = W1[(kb + j) * 128 + c];
  } else {
    const int f2 = f - 16, mf2 = f2 >> 3, ks = f2 & 7;
    const int o = 32 * mf2 + r, cb = ks * 16 + hh * 8;
#pragma unroll
    for (int j = 0; j < 8; ++j) v[j] = W2[(cb + j) * 128 + o];
  }
  uint4 d;
  d.x = cvtpk(v[0], v[1]); d.y = cvtpk(v[2], v[3]);
  d.z = cvtpk(v[4], v[5]); d.w = cvtpk(v[6], v[7]);
  Wf[(long long)f * 64 + l] = d;
}

// ---------------- CSR build ----------------
__global__ void k_hist(const int* __restrict__ ei, int* __restrict__ rowptr, int E){
  for (long long i = (long long)blockIdx.x * 256 + threadIdx.x; i < E;
       i += (long long)gridDim.x * 256)
    atomicAdd(&rowptr[ei[E + i]], 1);
}

__global__ __launch_bounds__(1024)
void k_scan(int* __restrict__ p, int N){
  __shared__ int ls[1024];
  const int t = threadIdx.x;
  const int chunk = (N + 1023) >> 10;
  const int c0 = t * chunk, c1 = min(N, c0 + chunk);
  int s = 0;
  for (int i = c0; i < c1; ++i) s += p[i];
  ls[t] = s;
  __syncthreads();
  for (int off = 1; off < 1024; off <<= 1) {
    int add = (t >= off) ? ls[t - off] : 0;
    __syncthreads();
    ls[t] += add;
    __syncthreads();
  }
  int run = (t == 0) ? 0 : ls[t - 1];
  for (int i = c0; i < c1; ++i) { int v = p[i]; p[i] = run; run += v; }
}

__global__ void k_fill(const int* __restrict__ ei, int* __restrict__ rowptr,
                       int* __restrict__ pose, int E){
  for (long long i = (long long)blockIdx.x * 256 + threadIdx.x; i < E;
       i += (long long)gridDim.x * 256) {
    int tg = ei[E + i];
    pose[i] = atomicAdd(&rowptr[tg], 1);
  }
}

// ---------------- K1: fused normalize + MLP (MFMA) + messages + scores ----------------
// Writes msgp rows and scoreS at CSR position pos=pose[e]; original-order score
// goes to scorig[e] (in-place over pose — read-before-write within the same wave).
__global__ __launch_bounds__(256)
void k1_fused(const float* __restrict__ x, const int* __restrict__ ei,
              const float* __restrict__ ea, const uint4* __restrict__ Wf,
              const float* __restrict__ b1, const float* __restrict__ b2,
              const float* __restrict__ attn, const int* __restrict__ pose,
              unsigned* __restrict__ msgp, float* __restrict__ scoreS,
              float* __restrict__ scorig, int E)
{
  const int lane = threadIdx.x & 63;
  const int wv   = threadIdx.x >> 6;
  const int h    = lane >> 5;
  const int r31  = lane & 31;
  const long long e   = (long long)blockIdx.x * 128 + wv * 32 + r31;
  const long long eld = (e < E) ? e : (long long)(E - 1);

  const int pos = pose[eld];
  const int src = ei[eld];

  // ---- load edge_attr + normalize ----
  float av[32];
  const float* earow = ea + eld * 64 + h * 8;
#pragma unroll
  for (int ks = 0; ks < 4; ++ks) {
    float4 p0 = *(const float4*)(earow + ks * 16);
    float4 p1 = *(const float4*)(earow + ks * 16 + 4);
    av[ks*8+0] = p0.x; av[ks*8+1] = p0.y; av[ks*8+2] = p0.z; av[ks*8+3] = p0.w;
    av[ks*8+4] = p1.x; av[ks*8+5] = p1.y; av[ks*8+6] = p1.z; av[ks*8+7] = p1.w;
  }
  float ss = 0.f;
#pragma unroll
  for (int i = 0; i < 32; ++i) ss = fmaf(av[i], av[i], ss);
  ss += __shfl_xor(ss, 32);
  const float rin = 1.0f / (sqrtf(ss) + 1e-8f);

  unsigned eb[4][4];
#pragma unroll
  for (int ks = 0; ks < 4; ++ks)
#pragma unroll
    for (int d = 0; d < 4; ++d)
      eb[ks][d] = cvtpk(av[ks*8+2*d] * rin, av[ks*8+2*d+1] * rin);

  // ---- prefetch x row, first half (channels 0..63), hidden under L1+tanh ----
  const float* xrow = x + (long long)src * 128;
  float4 xA[8];
#pragma unroll
  for (int i = 0; i < 8; ++i) {
    const int mf2 = i >> 2, rq = i & 3;
    xA[i] = *(const float4*)(xrow + 32*mf2 + 8*rq + 4*h);
  }
  asm volatile("" ::: "memory");   // pin load issue order

  // ---- L1 (staged per mf): h = tanh(ean @ W1 + b1), build B-fragments in-register ----
  unsigned hb[8][4];
#pragma unroll
  for (int mf = 0; mf < 4; ++mf) {
    f32x16 a1;
#pragma unroll
    for (int i = 0; i < 16; ++i) a1[i] = 0.f;
#pragma unroll
    for (int ks = 0; ks < 4; ++ks) {
      uint4 w = Wf[(mf * 4 + ks) * 64 + lane];
      a1 = __builtin_amdgcn_mfma_f32_32x32x16_bf16(
          frag_from(w.x, w.y, w.z, w.w),
          frag_from(eb[ks][0], eb[ks][1], eb[ks][2], eb[ks][3]), a1, 0, 0, 0);
    }
    float hv[16];
#pragma unroll
    for (int rq = 0; rq < 4; ++rq) {
      float4 bc = *(const float4*)(b1 + 32*mf + 8*rq + 4*h);
#pragma unroll
      for (int i = 0; i < 4; ++i) {
        float pre = a1[rq*4+i] + ((const float*)&bc)[i];
        float e2  = __expf(2.0f * pre);
        hv[rq*4+i] = 1.0f - 2.0f / (e2 + 1.0f);
      }
    }
#pragma unroll
    for (int q = 0; q < 2; ++q) {
      unsigned A = cvtpk(hv[q*8+0], hv[q*8+1]);
      unsigned B = cvtpk(hv[q*8+2], hv[q*8+3]);
      unsigned C = cvtpk(hv[q*8+4], hv[q*8+5]);
      unsigned D = cvtpk(hv[q*8+6], hv[q*8+7]);
      unsigned Axr = (unsigned)__shfl_xor((int)A, 32);
      unsigned Bxr = (unsigned)__shfl_xor((int)B, 32);
      unsigned Cxr = (unsigned)__shfl_xor((int)C, 32);
      unsigned Dxr = (unsigned)__shfl_xor((int)D, 32);
      hb[2*mf+q][0] = h ? Cxr : A;
      hb[2*mf+q][1] = h ? Dxr : B;
      hb[2*mf+q][2] = h ? C   : Axr;
      hb[2*mf+q][3] = h ? D   : Bxr;
    }
  }

  // ---- prefetch x row, second half (channels 64..127), hidden under L2 MFMAs ----
  float4 xB[8];
#pragma unroll
  for (int i = 0; i < 8; ++i) {
    const int mf2 = 2 + (i >> 2), rq = i & 3;
    xB[i] = *(const float4*)(xrow + 32*mf2 + 8*rq + 4*h);
  }
  asm volatile("" ::: "memory");

  // ---- L2 (staged per mf2) + epilogue ----
  float score = 0.f;
#pragma unroll
  for (int mf2 = 0; mf2 < 4; ++mf2) {
    f32x16 a2;
#pragma unroll
    for (int i = 0; i < 16; ++i) a2[i] = 0.f;
#pragma unroll
    for (int ks = 0; ks < 8; ++ks) {
      uint4 w = Wf[(16 + mf2 * 8 + ks) * 64 + lane];
      a2 = __builtin_amdgcn_mfma_f32_32x32x16_bf16(
          frag_from(w.x, w.y, w.z, w.w),
          frag_from(hb[ks][0], hb[ks][1], hb[ks][2], hb[ks][3]), a2, 0, 0, 0);
    }
    unsigned pk[8];
#pragma unroll
    for (int rq = 0; rq < 4; ++rq) {
      const int o0 = 32*mf2 + 8*rq + 4*h;
      float4 b2c = *(const float4*)(b2 + o0);
      float4 atc = *(const float4*)(attn + o0);
      float4 xc  = (mf2 < 2) ? xA[mf2*4+rq] : xB[(mf2-2)*4+rq];
      float m0 = (a2[rq*4+0] + b2c.x) * xc.x;
      float m1 = (a2[rq*4+1] + b2c.y) * xc.y;
      float m2 = (a2[rq*4+2] + b2c.z) * xc.z;
      float m3 = (a2[rq*4+3] + b2c.w) * xc.w;
      score = fmaf(m0, atc.x, score);
      score = fmaf(m1, atc.y, score);
      score = fmaf(m2, atc.z, score);
      score = fmaf(m3, atc.w, score);
      pk[2*rq]   = cvtpk(m0, m1);
      pk[2*rq+1] = cvtpk(m2, m3);
    }
    if (e < E) {
      // row layout: uint j = 16*mf2 + 8*h + 2*rq + half  (matches gather's decode)
      uint4* dst = (uint4*)(msgp + (long long)pos * 64 + 16*mf2 + 8*h);
      uint4 s0, s1;
      s0.x = pk[0]; s0.y = pk[1]; s0.z = pk[2]; s0.w = pk[3];
      s1.x = pk[4]; s1.y = pk[5]; s1.z = pk[6]; s1.w = pk[7];
      dst[0] = s0; dst[1] = s1;
    }
  }
  score += __shfl_xor(score, 32);
  if (h == 0 && e < E) {
    scoreS[pos] = score;
    scorig[e]   = score;   // overwrites pose[e] (already consumed by this wave)
  }
}

// ---------------- gather: per-node softmax + weighted sum (sequential streams) ----------------
__global__ __launch_bounds__(256)
void k_gather(const unsigned* __restrict__ msgp, const float* __restrict__ scoreS,
              const int* __restrict__ rowptr, float* __restrict__ lse,
              float* __restrict__ out, int N)
{
  const int lane = threadIdx.x & 63;
  const int node = blockIdx.x * 4 + (threadIdx.x >> 6);
  if (node >= N) return;
  const int end   = rowptr[node];
  const int start = node ? rowptr[node - 1] : 0;
  const int L     = end - start;

  float m = -3.4e38f, s = 0.f;
  for (int c0 = 0; c0 < L; c0 += 64) {
    const int j = c0 + lane;
    float sc = (j < L) ? scoreS[start + j] : -3.4e38f;
    float cm = sc;
#pragma unroll
    for (int off = 32; off; off >>= 1) cm = fmaxf(cm, __shfl_xor(cm, off));
    const float mn = fmaxf(m, cm);
    float ex = (j < L) ? __expf(sc - mn) : 0.f;
#pragma unroll
    for (int off = 32; off; off >>= 1) ex += __shfl_xor(ex, off);
    s = s * __expf(m - mn) + ex;
    m = mn;
  }
  const float lsev = m + logf(s + 1e-16f);
  if (lane == 0) lse[node] = lsev;

  float2 acc; acc.x = 0.f; acc.y = 0.f;
  for (int c0 = 0; c0 < L; c0 += 64) {
    const int j = c0 + lane;
    float w = (j < L) ? __expf(scoreS[start + j] - lsev) : 0.f;
    const int jn = min(64, L - c0);
#pragma unroll 4
    for (int j2 = 0; j2 < jn; ++j2) {
      float wj = __shfl(w, j2);
      unsigned md = msgp[(long long)(start + c0 + j2) * 64 + lane];
      acc.x = fmaf(wj, __uint_as_float(md << 16),          acc.x);
      acc.y = fmaf(wj, __uint_as_float(md & 0xffff0000u), acc.y);
    }
  }
  const int mf2 = lane >> 4, hh = (lane >> 3) & 1, rq = (lane >> 1) & 3, half = lane & 1;
  const int ch0 = 32*mf2 + 8*rq + 4*hh + 2*half;
  *(float2*)(out + (long long)node * 128 + ch0) = acc;
}

// ---------------- final attention weights (original edge order, in-place) ----------------
__global__ void k_wfin(float* __restrict__ wbuf, const int* __restrict__ ei,
                       const float* __restrict__ lse, int E){
  for (long long i = (long long)blockIdx.x * 256 + threadIdx.x; i < E;
       i += (long long)gridDim.x * 256) {
    float scv = wbuf[i];
    int tg = ei[E + i];
    wbuf[i] = __expf(scv - lse[tg]);
  }
}

extern "C" void kernel_launch(void* const* d_in, const int* in_sizes, int n_in,
                              void* d_out, int out_size, void* d_ws, size_t ws_size,
                              hipStream_t stream)
{
  const float* x    = (const float*)d_in[0];
  const int*   ei   = (const int*)d_in[1];
  const float* ea   = (const float*)d_in[2];
  const float* W1   = (const float*)d_in[3];
  const float* b1   = (const float*)d_in[4];
  const float* W2   = (const float*)d_in[5];
  const float* b2   = (const float*)d_in[6];
  const float* attn = (const float*)d_in[7];
  const int N = in_sizes[0] / 128;
  const int E = in_sizes[2] / 64;
  if (E <= 0 || N <= 0) return;

  float* out   = (float*)d_out;
  float* wregN = out + (long long)N * 128;   // E-float region: pose -> scores -> weights
  uint4* Wf    = (uint4*)d_out;              // node region start: W fragments (overwritten by gather)

  char* wsb = (char*)d_ws;
  unsigned* msgp   = (unsigned*)wsb;                                  // E*256 B
  float*    scoreS = (float*)(wsb + (size_t)E * 256);                 // E*4
  int*      rowptr = (int*)(wsb + (size_t)E * 256 + (size_t)E * 4);   // N*4
  float*    lse    = (float*)(wsb + (size_t)E * 260 + (size_t)N * 4); // N*4
  const size_t need = (size_t)E * 260 + (size_t)N * 8;
  if (ws_size < need) return;

  hipMemsetAsync(rowptr, 0, (size_t)N * 4, stream);
  k_prep<<<12, 256, 0, stream>>>(W1, W2, Wf);
  k_hist<<<1024, 256, 0, stream>>>(ei, rowptr, E);
  k_scan<<<1, 1024, 0, stream>>>(rowptr, N);
  k_fill<<<1024, 256, 0, stream>>>(ei, rowptr, (int*)wregN, E);
  k1_fused<<<(E + 127) / 128, 256, 0, stream>>>(x, ei, ea, Wf, b1, b2, attn,
                                                (const int*)wregN, msgp, scoreS,
                                                wregN, E);
  k_gather<<<(N + 3) / 4, 256, 0, stream>>>(msgp, scoreS, rowptr, lse, out, N);
  k_wfin<<<1024, 256, 0, stream>>>(wregN, ei, lse, E);
}